// Round 6
// baseline (194.969 us; speedup 1.0000x reference)
//
#include <hip/hip_runtime.h>
#include <hip/hip_bf16.h>
#include <math.h>

#define D_MODEL 1024
#define N_HEADS 16
#define HEAD_DIM 64
#define SEQ_T 2048
#define BATCH 2

typedef __attribute__((ext_vector_type(8))) short short8;
typedef __attribute__((ext_vector_type(4))) float f32x4;

__device__ __forceinline__ unsigned short f2bf(float f) {
    union { float f; unsigned int u; } v; v.f = f;
    return (unsigned short)((v.u + 0x7FFFu + ((v.u >> 16) & 1u)) >> 16);
}

__device__ __forceinline__ void glds16(const unsigned short* g, unsigned short* l) {
    __builtin_amdgcn_global_load_lds(
        (const __attribute__((address_space(1))) unsigned int*)g,
        (__attribute__((address_space(3))) unsigned int*)l, 16, 0, 0);
}

// ---------------- fused fp32 -> bf16 convert (x + 4 weights) ----------------
__global__ void cvt_all(const float4* __restrict__ x,
                        const float4* __restrict__ Wq, const float4* __restrict__ Wk,
                        const float4* __restrict__ Wv, const float4* __restrict__ Wp,
                        ushort4* __restrict__ xb, ushort4* __restrict__ wb,
                        ushort4* __restrict__ wpb) {
    int i = blockIdx.x * 256 + threadIdx.x;
    float4 v; ushort4* dst;
    if (i < 1048576) { v = x[i]; dst = xb + i; }
    else {
        int j = i - 1048576;
        int wsel = j >> 18;
        int o = j & 262143;
        const float4* s = wsel == 0 ? Wq : wsel == 1 ? Wk : wsel == 2 ? Wv : Wp;
        v = s[o];
        dst = (wsel == 3) ? (wpb + o) : (wb + (size_t)wsel * 262144 + o);
    }
    ushort4 u;
    u.x = f2bf(v.x); u.y = f2bf(v.y); u.z = f2bf(v.z); u.w = f2bf(v.w);
    *dst = u;
}

// ---------------- GEMM: C = A[M,K] * W[N,K]^T + bias (m97 structure, round-0) --------
// MODE 2: fp32 out row-major [M,1024], bias b0
// MODE 3: fused QKV: N=3072; q [B,H,T,Dh]; k [B,H,Tperm,Dh] (32-key permuted); v [B,H,Dh,T]
template<int MODE, int MTILE>
__global__ __launch_bounds__(256) void gemm2(
    const unsigned short* __restrict__ A,
    const unsigned short* __restrict__ W,
    const float* __restrict__ b0, const float* __restrict__ b1, const float* __restrict__ b2,
    void* __restrict__ o0, void* __restrict__ o1, void* __restrict__ o2)
{
    constexpr int K = 1024;
    constexpr int MT = MTILE / 32;
    constexpr int CAW = MTILE / 64;
    __shared__ unsigned short As[MTILE * 32];
    __shared__ unsigned short Bs[128 * 32];
    const int m0 = blockIdx.y * MTILE;
    const int n0 = blockIdx.x * 128;
    const int tid = threadIdx.x;
    const int w = tid >> 6, lane = tid & 63;
    const int col = lane & 15, quad = lane >> 4;
    const int wm = (w & 1) * (MTILE / 2), wn = (w >> 1) * 64;
    const int lr = lane >> 2, lc = (lane & 3) * 8;

    const f32x4 zero = {0.f, 0.f, 0.f, 0.f};
    f32x4 acc[MT][4];
#pragma unroll
    for (int i = 0; i < MT; i++)
#pragma unroll
        for (int j = 0; j < 4; j++) acc[i][j] = zero;

    for (int k0 = 0; k0 < K; k0 += 32) {
        __syncthreads();
#pragma unroll
        for (int c = 0; c < CAW; c++) {
            const int q = w * CAW + c;
            glds16(&A[(size_t)(m0 + q * 16 + lr) * K + k0 + lc], &As[q * 512]);
        }
#pragma unroll
        for (int c = 0; c < 2; c++) {
            const int q = w * 2 + c;
            glds16(&W[(size_t)(n0 + q * 16 + lr) * K + k0 + lc], &Bs[q * 512]);
        }
        __syncthreads();
        short8 af[MT], bf[4];
#pragma unroll
        for (int mt = 0; mt < MT; mt++)
            af[mt] = *(const short8*)&As[(wm + mt * 16 + col) * 32 + quad * 8];
#pragma unroll
        for (int nt = 0; nt < 4; nt++)
            bf[nt] = *(const short8*)&Bs[(wn + nt * 16 + col) * 32 + quad * 8];
#pragma unroll
        for (int mt = 0; mt < MT; mt++)
#pragma unroll
            for (int nt = 0; nt < 4; nt++)
                acc[mt][nt] = __builtin_amdgcn_mfma_f32_16x16x32_bf16(af[mt], bf[nt], acc[mt][nt], 0, 0, 0);
    }

#pragma unroll
    for (int mt = 0; mt < MT; mt++) {
#pragma unroll
        for (int nt = 0; nt < 4; nt++) {
            const int n = n0 + wn + nt * 16 + col;
            float bias;
            if constexpr (MODE == 2) bias = b0[n];
            else {
                const int sel = n >> 10, nq = n & 1023;
                bias = (sel == 0 ? b0 : sel == 1 ? b1 : b2)[nq];
            }
#pragma unroll
            for (int r = 0; r < 4; r++) {
                const int m = m0 + wm + mt * 16 + quad * 4 + r;
                const float v = acc[mt][nt][r] + bias;
                if constexpr (MODE == 2) {
                    ((float*)o0)[(size_t)m * 1024 + n] = v;
                } else {
                    const int sel = n >> 10, nq = n & 1023;
                    const int h = nq >> 6, dh = nq & 63, b = m >> 11, t = m & 2047;
                    if (sel < 2) {
                        unsigned short* dst = sel ? (unsigned short*)o1 : (unsigned short*)o0;
                        int tt = t;
                        if (sel == 1) {
                            // K permutation: pos (t16*16 + q*4 + r) <- key (q*8 + t16*4 + r)
                            const int tb = t & 31;
                            tt = (t & ~31) + ((tb & 4) << 2) + ((tb >> 3) << 2) + (tb & 3);
                        }
                        dst[(((size_t)(b * N_HEADS + h)) * SEQ_T + tt) * HEAD_DIM + dh] = f2bf(v);
                    } else {
                        ((unsigned short*)o2)[((size_t)(b * N_HEADS + h) * HEAD_DIM + dh) * SEQ_T + t] = f2bf(v);
                    }
                }
            }
        }
    }
}

// ---------------- flash attention v9: 32 q-rows/wave (MT=2) ----------------
// Block = 4 waves = one 128-query strip (4 sub-strips of 32 = 2x16 frags/wave),
// strip-pairs (s, 15-s) -> 256 uniform blocks of 34 key-tiles (1 block/CU).
// Halves LDS reads / HBM staging / barriers PER QUERY vs v8: K/V frags are read
// once per wave and reused across both 16-row q-frags.
// K/V staged via global_load_lds (16B) with XOR chunk swizzle, double-buffered,
// one barrier per tile. Softmax: absolute exp2 (folded scale), mask only where the
// tile crosses the wave's diagonal (wave-uniform), v_cvt_pk_bf16_f32 packing,
// setprio around MFMA clusters. Waves skip compute for tiles beyond their rows.
// Q: [BH,T,Dh] ; Kp: [BH,Tperm,Dh] (32-key permuted) ; Vt: [BH,Dh,T] ; Y: [B*T,D_MODEL]
__global__ __launch_bounds__(256) void flash9(
    const unsigned short* __restrict__ Q,
    const unsigned short* __restrict__ Kp,
    const unsigned short* __restrict__ Vt,
    unsigned short* __restrict__ Y)
{
    __shared__ unsigned short Ks[2][64 * 64];
    __shared__ unsigned short Vs[2][64 * 64];

    const int tid = threadIdx.x;
    const int w = tid >> 6, lane = tid & 63;
    const int col = lane & 15, quad = lane >> 4;
    const int i = blockIdx.x;
    const int bh = (i & 7) * 4 + ((i >> 3) & 3);  // same-bh blocks share XCD class
    const int sp = i >> 5;                        // strip-pair 0..7
    const int b = bh >> 4, h = bh & 15;

    const unsigned short* qbase = Q + (size_t)bh * SEQ_T * HEAD_DIM;
    const unsigned short* kbase = Kp + (size_t)bh * SEQ_T * HEAD_DIM;
    const unsigned short* vbase = Vt + (size_t)bh * HEAD_DIM * SEQ_T;

    const int srow = lane >> 3;                  // 0..7 within the wave's 8 rows
    const int schunk = (lane & 7) ^ srow;        // XOR-swizzled source chunk
    const int cswz = col & 7;                    // reader swizzle key (row&7 == col&7)

    const float SC2 = 0.18033688011f;            // 0.125 * log2(e): exp(s/8)=exp2(s*SC2)
    const f32x4 zero = {0.f, 0.f, 0.f, 0.f};

    for (int ti = 0; ti < 2; ti++) {
        const int s = ti ? (15 - sp) : sp;
        const int qrow = s * 128 + w * 32;       // this wave's 32-row sub-strip
        short8 qf[2][2];
#pragma unroll
        for (int m = 0; m < 2; m++) {
            qf[m][0] = *(const short8*)&qbase[(size_t)(qrow + m * 16 + col) * HEAD_DIM + quad * 8];
            qf[m][1] = *(const short8*)&qbase[(size_t)(qrow + m * 16 + col) * HEAD_DIM + quad * 8 + 32];
        }

        f32x4 acc[2][4];
#pragma unroll
        for (int m = 0; m < 2; m++)
#pragma unroll
            for (int nt = 0; nt < 4; nt++) acc[m][nt] = zero;
        float l[2] = {0.f, 0.f};

        const int nk = 2 * s + 2;

        __syncthreads();   // previous ti's readers done before overwriting buf 0
        // prefetch kt=0 into buffer 0
#pragma unroll
        for (int rq = 0; rq < 2; rq++) {
            const int rr = rq * 32 + 8 * w;      // wave-uniform row base
            glds16(&kbase[(size_t)(rr + srow) * HEAD_DIM + schunk * 8], &Ks[0][rr * 64]);
            glds16(&vbase[(size_t)(rr + srow) * SEQ_T + schunk * 8], &Vs[0][rr * 64]);
        }

        int cur = 0;
        for (int kt = 0; kt < nk; kt++) {
            const int kb = kt * 64;
            __syncthreads();   // vmcnt(0) drain: buf[cur] ready; buf[cur^1] readers done

            if (kt + 1 < nk) {
                const int kb2 = kb + 64;
#pragma unroll
                for (int rq = 0; rq < 2; rq++) {
                    const int rr = rq * 32 + 8 * w;
                    glds16(&kbase[(size_t)(kb2 + rr + srow) * HEAD_DIM + schunk * 8], &Ks[cur ^ 1][rr * 64]);
                    glds16(&vbase[(size_t)(rr + srow) * SEQ_T + kb2 + schunk * 8], &Vs[cur ^ 1][rr * 64]);
                }
            }

            // waves whose 32 q-rows all precede this key tile do no compute
            // (staging + barriers above stay uniform across the block)
            if (kb <= qrow + 31) {
                const unsigned short* ks = Ks[cur];
                const unsigned short* vs = Vs[cur];

                // V B-frags from LDS (swizzled chunks) — shared by both q-frags
                short8 vB[2][4];
#pragma unroll
                for (int g = 0; g < 2; g++)
#pragma unroll
                    for (int nt = 0; nt < 4; nt++)
                        vB[g][nt] = *(const short8*)&vs[(nt * 16 + col) * 64 + (((g * 4 + quad) ^ cswz) * 8)];

                // St[m] = K*Q[m]^T over 4 16-key tiles; K frags read ONCE for both m
                f32x4 St[2][4];
                __builtin_amdgcn_s_setprio(1);
#pragma unroll
                for (int kc = 0; kc < 4; kc++) {
                    const short8 kf0 = *(const short8*)&ks[(kc * 16 + col) * 64 + ((quad ^ cswz) * 8)];
                    const short8 kf1 = *(const short8*)&ks[(kc * 16 + col) * 64 + (((quad + 4) ^ cswz) * 8)];
#pragma unroll
                    for (int m = 0; m < 2; m++) {
                        f32x4 z = zero;
                        z = __builtin_amdgcn_mfma_f32_16x16x32_bf16(kf0, qf[m][0], z, 0, 0, 0);
                        z = __builtin_amdgcn_mfma_f32_16x16x32_bf16(kf1, qf[m][1], z, 0, 0, 0);
                        St[m][kc] = z;
                    }
                }
                __builtin_amdgcn_s_setprio(0);

                // softmax + PV per q-frag; mask only when tile crosses this wave's diag
                // actual key of St[m][kc][r] = kb + (kc>>1)*32 + quad*8 + (kc&1)*4 + r
                const bool needMask = (kb + 63 > qrow);
#pragma unroll
                for (int m = 0; m < 2; m++) {
                    const int qq = qrow + m * 16 + col;
                    short8 pA[2];
                    if (needMask) {
#pragma unroll
                        for (int g = 0; g < 2; g++) {
                            union { short8 s; __hip_bfloat162 h[4]; } pu;
#pragma unroll
                            for (int t16 = 0; t16 < 2; t16++) {
                                const int kc = 2 * g + t16;
                                const int kbase_c = kb + (kc >> 1) * 32 + quad * 8 + (kc & 1) * 4;
                                float p[4];
#pragma unroll
                                for (int r = 0; r < 4; r++) {
                                    p[r] = __builtin_amdgcn_exp2f(St[m][kc][r] * SC2);
                                    if (kbase_c + r > qq) p[r] = 0.f;
                                    l[m] += p[r];
                                }
                                pu.h[t16 * 2]     = __float22bfloat162_rn(make_float2(p[0], p[1]));
                                pu.h[t16 * 2 + 1] = __float22bfloat162_rn(make_float2(p[2], p[3]));
                            }
                            pA[g] = pu.s;
                        }
                    } else {
#pragma unroll
                        for (int g = 0; g < 2; g++) {
                            union { short8 s; __hip_bfloat162 h[4]; } pu;
#pragma unroll
                            for (int t16 = 0; t16 < 2; t16++) {
                                const int kc = 2 * g + t16;
                                float p[4];
#pragma unroll
                                for (int r = 0; r < 4; r++) {
                                    p[r] = __builtin_amdgcn_exp2f(St[m][kc][r] * SC2);
                                    l[m] += p[r];
                                }
                                pu.h[t16 * 2]     = __float22bfloat162_rn(make_float2(p[0], p[1]));
                                pu.h[t16 * 2 + 1] = __float22bfloat162_rn(make_float2(p[2], p[3]));
                            }
                            pA[g] = pu.s;
                        }
                    }

                    __builtin_amdgcn_s_setprio(1);
#pragma unroll
                    for (int g = 0; g < 2; g++)
#pragma unroll
                        for (int nt = 0; nt < 4; nt++)
                            acc[m][nt] = __builtin_amdgcn_mfma_f32_16x16x32_bf16(pA[g], vB[g][nt], acc[m][nt], 0, 0, 0);
                    __builtin_amdgcn_s_setprio(0);
                }
            }

            cur ^= 1;
        }

        // cross-lane reduction + write, per q-frag
#pragma unroll
        for (int m = 0; m < 2; m++) {
            float lm = l[m];
            lm += __shfl_xor(lm, 16);
            lm += __shfl_xor(lm, 32);
            const float linv = 1.0f / lm;
            float lr[4];
#pragma unroll
            for (int r = 0; r < 4; r++) lr[r] = __shfl(linv, quad * 4 + r);
#pragma unroll
            for (int nt = 0; nt < 4; nt++)
#pragma unroll
                for (int r = 0; r < 4; r++) {
                    const int qg = qrow + m * 16 + quad * 4 + r;
                    Y[((size_t)(b * SEQ_T + qg)) * D_MODEL + h * HEAD_DIM + nt * 16 + col] =
                        f2bf(acc[m][nt][r] * lr[r]);
                }
        }
    }
}

extern "C" void kernel_launch(void* const* d_in, const int* in_sizes, int n_in,
                              void* d_out, int out_size, void* d_ws, size_t ws_size,
                              hipStream_t stream) {
    const float* x  = (const float*)d_in[0];
    const float* Wq = (const float*)d_in[1];
    const float* bq = (const float*)d_in[2];
    const float* Wk = (const float*)d_in[3];
    const float* bk = (const float*)d_in[4];
    const float* Wv = (const float*)d_in[5];
    const float* bv = (const float*)d_in[6];
    const float* Wp = (const float*)d_in[7];
    const float* bp = (const float*)d_in[8];
    float* out = (float*)d_out;

    char* ws = (char*)d_ws;
    const size_t XSZ = (size_t)4096 * 1024 * 2;
    unsigned short* xb  = (unsigned short*)ws;  ws += XSZ;
    unsigned short* wb  = (unsigned short*)ws;  ws += (size_t)3072 * 1024 * 2;
    unsigned short* wpb = (unsigned short*)ws;  ws += (size_t)1024 * 1024 * 2;
    unsigned short* qb  = (unsigned short*)ws;  ws += XSZ;
    unsigned short* kb  = (unsigned short*)ws;  ws += XSZ;  // permuted keys
    unsigned short* vtb = (unsigned short*)ws;  ws += XSZ;
    unsigned short* yb  = (unsigned short*)ws;  ws += XSZ;

    cvt_all<<<8192, 256, 0, stream>>>((const float4*)x, (const float4*)Wq, (const float4*)Wk,
                                      (const float4*)Wv, (const float4*)Wp,
                                      (ushort4*)xb, (ushort4*)wb, (ushort4*)wpb);

    gemm2<3, 128><<<dim3(24, 32), 256, 0, stream>>>(xb, wb, bq, bk, bv, qb, kb, vtb);

    flash9<<<256, 256, 0, stream>>>(qb, kb, vtb, yb);

    gemm2<2, 64><<<dim3(8, 64), 256, 0, stream>>>(yb, wpb, bp, nullptr, nullptr, out, nullptr, nullptr);
}

// Round 7
// 192.189 us; speedup vs baseline: 1.0145x; 1.0145x over previous
//
#include <hip/hip_runtime.h>
#include <hip/hip_bf16.h>
#include <math.h>

#define D_MODEL 1024
#define N_HEADS 16
#define HEAD_DIM 64
#define SEQ_T 2048
#define BATCH 2

typedef __attribute__((ext_vector_type(8))) short short8;
typedef __attribute__((ext_vector_type(4))) float f32x4;

__device__ __forceinline__ unsigned short f2bf(float f) {
    union { float f; unsigned int u; } v; v.f = f;
    return (unsigned short)((v.u + 0x7FFFu + ((v.u >> 16) & 1u)) >> 16);
}

__device__ __forceinline__ void glds16(const unsigned short* g, unsigned short* l) {
    __builtin_amdgcn_global_load_lds(
        (const __attribute__((address_space(1))) unsigned int*)g,
        (__attribute__((address_space(3))) unsigned int*)l, 16, 0, 0);
}

// ---------------- fused fp32 -> bf16 convert (x + 4 weights) ----------------
__global__ void cvt_all(const float4* __restrict__ x,
                        const float4* __restrict__ Wq, const float4* __restrict__ Wk,
                        const float4* __restrict__ Wv, const float4* __restrict__ Wp,
                        ushort4* __restrict__ xb, ushort4* __restrict__ wb,
                        ushort4* __restrict__ wpb) {
    int i = blockIdx.x * 256 + threadIdx.x;
    float4 v; ushort4* dst;
    if (i < 1048576) { v = x[i]; dst = xb + i; }
    else {
        int j = i - 1048576;
        int wsel = j >> 18;
        int o = j & 262143;
        const float4* s = wsel == 0 ? Wq : wsel == 1 ? Wk : wsel == 2 ? Wv : Wp;
        v = s[o];
        dst = (wsel == 3) ? (wpb + o) : (wb + (size_t)wsel * 262144 + o);
    }
    ushort4 u;
    u.x = f2bf(v.x); u.y = f2bf(v.y); u.z = f2bf(v.z); u.w = f2bf(v.w);
    *dst = u;
}

// ---------------- GEMM: C = A[M,K] * W[N,K]^T + bias (m97 structure, round-0) --------
// MODE 2: fp32 out row-major [M,1024], bias b0
// MODE 3: fused QKV: N=3072; q [B,H,T,Dh]; k [B,H,Tperm,Dh] (32-key permuted); v [B,H,Dh,T]
template<int MODE, int MTILE>
__global__ __launch_bounds__(256) void gemm2(
    const unsigned short* __restrict__ A,
    const unsigned short* __restrict__ W,
    const float* __restrict__ b0, const float* __restrict__ b1, const float* __restrict__ b2,
    void* __restrict__ o0, void* __restrict__ o1, void* __restrict__ o2)
{
    constexpr int K = 1024;
    constexpr int MT = MTILE / 32;
    constexpr int CAW = MTILE / 64;
    __shared__ unsigned short As[MTILE * 32];
    __shared__ unsigned short Bs[128 * 32];
    const int m0 = blockIdx.y * MTILE;
    const int n0 = blockIdx.x * 128;
    const int tid = threadIdx.x;
    const int w = tid >> 6, lane = tid & 63;
    const int col = lane & 15, quad = lane >> 4;
    const int wm = (w & 1) * (MTILE / 2), wn = (w >> 1) * 64;
    const int lr = lane >> 2, lc = (lane & 3) * 8;

    const f32x4 zero = {0.f, 0.f, 0.f, 0.f};
    f32x4 acc[MT][4];
#pragma unroll
    for (int i = 0; i < MT; i++)
#pragma unroll
        for (int j = 0; j < 4; j++) acc[i][j] = zero;

    for (int k0 = 0; k0 < K; k0 += 32) {
        __syncthreads();
#pragma unroll
        for (int c = 0; c < CAW; c++) {
            const int q = w * CAW + c;
            glds16(&A[(size_t)(m0 + q * 16 + lr) * K + k0 + lc], &As[q * 512]);
        }
#pragma unroll
        for (int c = 0; c < 2; c++) {
            const int q = w * 2 + c;
            glds16(&W[(size_t)(n0 + q * 16 + lr) * K + k0 + lc], &Bs[q * 512]);
        }
        __syncthreads();
        short8 af[MT], bf[4];
#pragma unroll
        for (int mt = 0; mt < MT; mt++)
            af[mt] = *(const short8*)&As[(wm + mt * 16 + col) * 32 + quad * 8];
#pragma unroll
        for (int nt = 0; nt < 4; nt++)
            bf[nt] = *(const short8*)&Bs[(wn + nt * 16 + col) * 32 + quad * 8];
#pragma unroll
        for (int mt = 0; mt < MT; mt++)
#pragma unroll
            for (int nt = 0; nt < 4; nt++)
                acc[mt][nt] = __builtin_amdgcn_mfma_f32_16x16x32_bf16(af[mt], bf[nt], acc[mt][nt], 0, 0, 0);
    }

#pragma unroll
    for (int mt = 0; mt < MT; mt++) {
#pragma unroll
        for (int nt = 0; nt < 4; nt++) {
            const int n = n0 + wn + nt * 16 + col;
            float bias;
            if constexpr (MODE == 2) bias = b0[n];
            else {
                const int sel = n >> 10, nq = n & 1023;
                bias = (sel == 0 ? b0 : sel == 1 ? b1 : b2)[nq];
            }
#pragma unroll
            for (int r = 0; r < 4; r++) {
                const int m = m0 + wm + mt * 16 + quad * 4 + r;
                const float v = acc[mt][nt][r] + bias;
                if constexpr (MODE == 2) {
                    ((float*)o0)[(size_t)m * 1024 + n] = v;
                } else {
                    const int sel = n >> 10, nq = n & 1023;
                    const int h = nq >> 6, dh = nq & 63, b = m >> 11, t = m & 2047;
                    if (sel < 2) {
                        unsigned short* dst = sel ? (unsigned short*)o1 : (unsigned short*)o0;
                        int tt = t;
                        if (sel == 1) {
                            // K permutation: pos (t16*16 + q*4 + r) <- key (q*8 + t16*4 + r)
                            const int tb = t & 31;
                            tt = (t & ~31) + ((tb & 4) << 2) + ((tb >> 3) << 2) + (tb & 3);
                        }
                        dst[(((size_t)(b * N_HEADS + h)) * SEQ_T + tt) * HEAD_DIM + dh] = f2bf(v);
                    } else {
                        ((unsigned short*)o2)[((size_t)(b * N_HEADS + h) * HEAD_DIM + dh) * SEQ_T + t] = f2bf(v);
                    }
                }
            }
        }
    }
}

// ---------------- flash attention v10: 2-wave blocks, MT=2, 4 blocks/CU --------------
// Block = 2 waves = one 64-query tile (2 sub-strips of 32 = 2x16 frags/wave).
// Grid 1024 x 128thr -> 4 independent blocks/CU (8 waves/CU): restores the block-level
// overlap flash9 lost (it had 1 block/CU, OccupancyPercent 9.6, everything serialized)
// while KEEPING flash9's MT=2 win (K/V LDS frags read once, reused for 2 q-frags =
// half the ds_read_b128 of flash8 per tile-instance).
// Balance: per-CU-slot permutation gives the 4 blocks on one CU qt = {q0, 31-q0,
// q0+8, 23-q0} -> uniform 66 tiles/CU (no ti loop, no skip branch: kb <= qrow always).
// K/V staged via global_load_lds (16B, XOR chunk swizzle), double-buffered, one
// barrier per tile. Softmax: absolute exp2 (folded scale), diag-tile-only mask,
// v_cvt_pk_bf16_f32 packing, setprio around MFMA clusters.
// Q: [BH,T,Dh] ; Kp: [BH,Tperm,Dh] (32-key permuted) ; Vt: [BH,Dh,T] ; Y: [B*T,D_MODEL]
__global__ __launch_bounds__(128) void flash10(
    const unsigned short* __restrict__ Q,
    const unsigned short* __restrict__ Kp,
    const unsigned short* __restrict__ Vt,
    unsigned short* __restrict__ Y)
{
    __shared__ unsigned short Ks[2][64 * 64];
    __shared__ unsigned short Vs[2][64 * 64];

    const int tid = threadIdx.x;
    const int w = tid >> 6, lane = tid & 63;
    const int col = lane & 15, quad = lane >> 4;
    const int i = blockIdx.x;
    const int g = i & 255, r4 = i >> 8;           // CU slot, round
    const int bh = (g & 7) * 4 + ((g >> 3) & 3);  // same-bh blocks share XCD class
    const int q0 = g >> 5;                        // 0..7
    const int qt = (r4 == 0) ? q0 : (r4 == 1) ? (31 - q0)
                 : (r4 == 2) ? (q0 + 8) : (23 - q0);   // per-CU sum uniform (66 tiles)
    const int b = bh >> 4, h = bh & 15;

    const unsigned short* qbase = Q + (size_t)bh * SEQ_T * HEAD_DIM;
    const unsigned short* kbase = Kp + (size_t)bh * SEQ_T * HEAD_DIM;
    const unsigned short* vbase = Vt + (size_t)bh * HEAD_DIM * SEQ_T;

    const int srow = lane >> 3;                  // 0..7 within an 8-row group
    const int schunk = (lane & 7) ^ srow;        // XOR-swizzled source chunk
    const int cswz = col & 7;                    // reader swizzle key (row&7 == col&7)

    const float SC2 = 0.18033688011f;            // 0.125 * log2(e): exp(s/8)=exp2(s*SC2)
    const f32x4 zero = {0.f, 0.f, 0.f, 0.f};

    const int qrow = qt * 64 + w * 32;           // this wave's 32-row sub-strip
    short8 qf[2][2];
#pragma unroll
    for (int m = 0; m < 2; m++) {
        qf[m][0] = *(const short8*)&qbase[(size_t)(qrow + m * 16 + col) * HEAD_DIM + quad * 8];
        qf[m][1] = *(const short8*)&qbase[(size_t)(qrow + m * 16 + col) * HEAD_DIM + quad * 8 + 32];
    }

    f32x4 acc[2][4];
#pragma unroll
    for (int m = 0; m < 2; m++)
#pragma unroll
        for (int nt = 0; nt < 4; nt++) acc[m][nt] = zero;
    float l[2] = {0.f, 0.f};

    const int nk = qt + 1;

    // prefetch kt=0 into buffer 0 (4 rounds x 16 rows; 2 waves cover 64 rows)
#pragma unroll
    for (int rq = 0; rq < 4; rq++) {
        const int rr = rq * 16 + 8 * w;          // wave-uniform row base
        glds16(&kbase[(size_t)(rr + srow) * HEAD_DIM + schunk * 8], &Ks[0][rr * 64]);
        glds16(&vbase[(size_t)(rr + srow) * SEQ_T + schunk * 8], &Vs[0][rr * 64]);
    }

    int cur = 0;
    for (int kt = 0; kt < nk; kt++) {
        const int kb = kt * 64;
        __syncthreads();   // vmcnt(0) drain: buf[cur] ready; buf[cur^1] readers done

        if (kt + 1 < nk) {
            const int kb2 = kb + 64;
#pragma unroll
            for (int rq = 0; rq < 4; rq++) {
                const int rr = rq * 16 + 8 * w;
                glds16(&kbase[(size_t)(kb2 + rr + srow) * HEAD_DIM + schunk * 8], &Ks[cur ^ 1][rr * 64]);
                glds16(&vbase[(size_t)(rr + srow) * SEQ_T + kb2 + schunk * 8], &Vs[cur ^ 1][rr * 64]);
            }
        }

        const unsigned short* ks = Ks[cur];
        const unsigned short* vs = Vs[cur];

        // V B-frags from LDS (swizzled chunks) — shared by both q-frags
        short8 vB[2][4];
#pragma unroll
        for (int gg = 0; gg < 2; gg++)
#pragma unroll
            for (int nt = 0; nt < 4; nt++)
                vB[gg][nt] = *(const short8*)&vs[(nt * 16 + col) * 64 + (((gg * 4 + quad) ^ cswz) * 8)];

        // St[m] = K*Q[m]^T over 4 16-key tiles; K frags read ONCE for both m
        f32x4 St[2][4];
        __builtin_amdgcn_s_setprio(1);
#pragma unroll
        for (int kc = 0; kc < 4; kc++) {
            const short8 kf0 = *(const short8*)&ks[(kc * 16 + col) * 64 + ((quad ^ cswz) * 8)];
            const short8 kf1 = *(const short8*)&ks[(kc * 16 + col) * 64 + (((quad + 4) ^ cswz) * 8)];
#pragma unroll
            for (int m = 0; m < 2; m++) {
                f32x4 z = zero;
                z = __builtin_amdgcn_mfma_f32_16x16x32_bf16(kf0, qf[m][0], z, 0, 0, 0);
                z = __builtin_amdgcn_mfma_f32_16x16x32_bf16(kf1, qf[m][1], z, 0, 0, 0);
                St[m][kc] = z;
            }
        }
        __builtin_amdgcn_s_setprio(0);

        // softmax + PV per q-frag; mask only on the diagonal tile (wave-uniform)
        // actual key of St[m][kc][r] = kb + (kc>>1)*32 + quad*8 + (kc&1)*4 + r
        const bool diag = (kt == nk - 1);
#pragma unroll
        for (int m = 0; m < 2; m++) {
            const int qq = qrow + m * 16 + col;
            short8 pA[2];
            if (diag) {
#pragma unroll
                for (int gg = 0; gg < 2; gg++) {
                    union { short8 s; __hip_bfloat162 h[4]; } pu;
#pragma unroll
                    for (int t16 = 0; t16 < 2; t16++) {
                        const int kc = 2 * gg + t16;
                        const int kbase_c = kb + (kc >> 1) * 32 + quad * 8 + (kc & 1) * 4;
                        float p[4];
#pragma unroll
                        for (int r = 0; r < 4; r++) {
                            p[r] = __builtin_amdgcn_exp2f(St[m][kc][r] * SC2);
                            if (kbase_c + r > qq) p[r] = 0.f;
                            l[m] += p[r];
                        }
                        pu.h[t16 * 2]     = __float22bfloat162_rn(make_float2(p[0], p[1]));
                        pu.h[t16 * 2 + 1] = __float22bfloat162_rn(make_float2(p[2], p[3]));
                    }
                    pA[gg] = pu.s;
                }
            } else {
#pragma unroll
                for (int gg = 0; gg < 2; gg++) {
                    union { short8 s; __hip_bfloat162 h[4]; } pu;
#pragma unroll
                    for (int t16 = 0; t16 < 2; t16++) {
                        const int kc = 2 * gg + t16;
                        float p[4];
#pragma unroll
                        for (int r = 0; r < 4; r++) {
                            p[r] = __builtin_amdgcn_exp2f(St[m][kc][r] * SC2);
                            l[m] += p[r];
                        }
                        pu.h[t16 * 2]     = __float22bfloat162_rn(make_float2(p[0], p[1]));
                        pu.h[t16 * 2 + 1] = __float22bfloat162_rn(make_float2(p[2], p[3]));
                    }
                    pA[gg] = pu.s;
                }
            }

            __builtin_amdgcn_s_setprio(1);
#pragma unroll
            for (int gg = 0; gg < 2; gg++)
#pragma unroll
                for (int nt = 0; nt < 4; nt++)
                    acc[m][nt] = __builtin_amdgcn_mfma_f32_16x16x32_bf16(pA[gg], vB[gg][nt], acc[m][nt], 0, 0, 0);
            __builtin_amdgcn_s_setprio(0);
        }

        cur ^= 1;
    }

    // cross-lane reduction + write, per q-frag
#pragma unroll
    for (int m = 0; m < 2; m++) {
        float lm = l[m];
        lm += __shfl_xor(lm, 16);
        lm += __shfl_xor(lm, 32);
        const float linv = 1.0f / lm;
        float lr[4];
#pragma unroll
        for (int r = 0; r < 4; r++) lr[r] = __shfl(linv, quad * 4 + r);
#pragma unroll
        for (int nt = 0; nt < 4; nt++)
#pragma unroll
            for (int r = 0; r < 4; r++) {
                const int qg = qrow + m * 16 + quad * 4 + r;
                Y[((size_t)(b * SEQ_T + qg)) * D_MODEL + h * HEAD_DIM + nt * 16 + col] =
                    f2bf(acc[m][nt][r] * lr[r]);
            }
    }
}

extern "C" void kernel_launch(void* const* d_in, const int* in_sizes, int n_in,
                              void* d_out, int out_size, void* d_ws, size_t ws_size,
                              hipStream_t stream) {
    const float* x  = (const float*)d_in[0];
    const float* Wq = (const float*)d_in[1];
    const float* bq = (const float*)d_in[2];
    const float* Wk = (const float*)d_in[3];
    const float* bk = (const float*)d_in[4];
    const float* Wv = (const float*)d_in[5];
    const float* bv = (const float*)d_in[6];
    const float* Wp = (const float*)d_in[7];
    const float* bp = (const float*)d_in[8];
    float* out = (float*)d_out;

    char* ws = (char*)d_ws;
    const size_t XSZ = (size_t)4096 * 1024 * 2;
    unsigned short* xb  = (unsigned short*)ws;  ws += XSZ;
    unsigned short* wb  = (unsigned short*)ws;  ws += (size_t)3072 * 1024 * 2;
    unsigned short* wpb = (unsigned short*)ws;  ws += (size_t)1024 * 1024 * 2;
    unsigned short* qb  = (unsigned short*)ws;  ws += XSZ;
    unsigned short* kb  = (unsigned short*)ws;  ws += XSZ;  // permuted keys
    unsigned short* vtb = (unsigned short*)ws;  ws += XSZ;
    unsigned short* yb  = (unsigned short*)ws;  ws += XSZ;

    cvt_all<<<8192, 256, 0, stream>>>((const float4*)x, (const float4*)Wq, (const float4*)Wk,
                                      (const float4*)Wv, (const float4*)Wp,
                                      (ushort4*)xb, (ushort4*)wb, (ushort4*)wpb);

    gemm2<3, 128><<<dim3(24, 32), 256, 0, stream>>>(xb, wb, bq, bk, bv, qb, kb, vtb);

    flash10<<<1024, 128, 0, stream>>>(qb, kb, vtb, yb);

    gemm2<2, 64><<<dim3(8, 64), 256, 0, stream>>>(yb, wpb, bp, nullptr, nullptr, out, nullptr, nullptr);
}

// Round 8
// 184.016 us; speedup vs baseline: 1.0595x; 1.0444x over previous
//
#include <hip/hip_runtime.h>
#include <hip/hip_bf16.h>
#include <math.h>

#define D_MODEL 1024
#define N_HEADS 16
#define HEAD_DIM 64
#define SEQ_T 2048
#define BATCH 2

typedef __attribute__((ext_vector_type(8))) short short8;
typedef __attribute__((ext_vector_type(4))) float f32x4;

__device__ __forceinline__ unsigned short f2bf(float f) {
    union { float f; unsigned int u; } v; v.f = f;
    return (unsigned short)((v.u + 0x7FFFu + ((v.u >> 16) & 1u)) >> 16);
}

__device__ __forceinline__ void glds16(const unsigned short* g, unsigned short* l) {
    __builtin_amdgcn_global_load_lds(
        (const __attribute__((address_space(1))) unsigned int*)g,
        (__attribute__((address_space(3))) unsigned int*)l, 16, 0, 0);
}

// ---------------- fused fp32 -> bf16 convert (x + 4 weights) ----------------
__global__ void cvt_all(const float4* __restrict__ x,
                        const float4* __restrict__ Wq, const float4* __restrict__ Wk,
                        const float4* __restrict__ Wv, const float4* __restrict__ Wp,
                        ushort4* __restrict__ xb, ushort4* __restrict__ wb,
                        ushort4* __restrict__ wpb) {
    int i = blockIdx.x * 256 + threadIdx.x;
    float4 v; ushort4* dst;
    if (i < 1048576) { v = x[i]; dst = xb + i; }
    else {
        int j = i - 1048576;
        int wsel = j >> 18;
        int o = j & 262143;
        const float4* s = wsel == 0 ? Wq : wsel == 1 ? Wk : wsel == 2 ? Wv : Wp;
        v = s[o];
        dst = (wsel == 3) ? (wpb + o) : (wb + (size_t)wsel * 262144 + o);
    }
    ushort4 u;
    u.x = f2bf(v.x); u.y = f2bf(v.y); u.z = f2bf(v.z); u.w = f2bf(v.w);
    *dst = u;
}

// ---------------- GEMM: C = A[M,K] * W[N,K]^T + bias (m97 structure, round-0) --------
// MODE 2: fp32 out row-major [M,1024], bias b0
// MODE 3: fused QKV: N=3072; q [B,H,T,Dh]; k [B,H,Tperm,Dh] (32-key permuted); v [B,H,Dh,T]
template<int MODE, int MTILE>
__global__ __launch_bounds__(256) void gemm2(
    const unsigned short* __restrict__ A,
    const unsigned short* __restrict__ W,
    const float* __restrict__ b0, const float* __restrict__ b1, const float* __restrict__ b2,
    void* __restrict__ o0, void* __restrict__ o1, void* __restrict__ o2)
{
    constexpr int K = 1024;
    constexpr int MT = MTILE / 32;
    constexpr int CAW = MTILE / 64;
    __shared__ unsigned short As[MTILE * 32];
    __shared__ unsigned short Bs[128 * 32];
    const int m0 = blockIdx.y * MTILE;
    const int n0 = blockIdx.x * 128;
    const int tid = threadIdx.x;
    const int w = tid >> 6, lane = tid & 63;
    const int col = lane & 15, quad = lane >> 4;
    const int wm = (w & 1) * (MTILE / 2), wn = (w >> 1) * 64;
    const int lr = lane >> 2, lc = (lane & 3) * 8;

    const f32x4 zero = {0.f, 0.f, 0.f, 0.f};
    f32x4 acc[MT][4];
#pragma unroll
    for (int i = 0; i < MT; i++)
#pragma unroll
        for (int j = 0; j < 4; j++) acc[i][j] = zero;

    for (int k0 = 0; k0 < K; k0 += 32) {
        __syncthreads();
#pragma unroll
        for (int c = 0; c < CAW; c++) {
            const int q = w * CAW + c;
            glds16(&A[(size_t)(m0 + q * 16 + lr) * K + k0 + lc], &As[q * 512]);
        }
#pragma unroll
        for (int c = 0; c < 2; c++) {
            const int q = w * 2 + c;
            glds16(&W[(size_t)(n0 + q * 16 + lr) * K + k0 + lc], &Bs[q * 512]);
        }
        __syncthreads();
        short8 af[MT], bf[4];
#pragma unroll
        for (int mt = 0; mt < MT; mt++)
            af[mt] = *(const short8*)&As[(wm + mt * 16 + col) * 32 + quad * 8];
#pragma unroll
        for (int nt = 0; nt < 4; nt++)
            bf[nt] = *(const short8*)&Bs[(wn + nt * 16 + col) * 32 + quad * 8];
#pragma unroll
        for (int mt = 0; mt < MT; mt++)
#pragma unroll
            for (int nt = 0; nt < 4; nt++)
                acc[mt][nt] = __builtin_amdgcn_mfma_f32_16x16x32_bf16(af[mt], bf[nt], acc[mt][nt], 0, 0, 0);
    }

#pragma unroll
    for (int mt = 0; mt < MT; mt++) {
#pragma unroll
        for (int nt = 0; nt < 4; nt++) {
            const int n = n0 + wn + nt * 16 + col;
            float bias;
            if constexpr (MODE == 2) bias = b0[n];
            else {
                const int sel = n >> 10, nq = n & 1023;
                bias = (sel == 0 ? b0 : sel == 1 ? b1 : b2)[nq];
            }
#pragma unroll
            for (int r = 0; r < 4; r++) {
                const int m = m0 + wm + mt * 16 + quad * 4 + r;
                const float v = acc[mt][nt][r] + bias;
                if constexpr (MODE == 2) {
                    ((float*)o0)[(size_t)m * 1024 + n] = v;
                } else {
                    const int sel = n >> 10, nq = n & 1023;
                    const int h = nq >> 6, dh = nq & 63, b = m >> 11, t = m & 2047;
                    if (sel < 2) {
                        unsigned short* dst = sel ? (unsigned short*)o1 : (unsigned short*)o0;
                        int tt = t;
                        if (sel == 1) {
                            // K permutation: pos (t16*16 + q*4 + r) <- key (q*8 + t16*4 + r)
                            const int tb = t & 31;
                            tt = (t & ~31) + ((tb & 4) << 2) + ((tb >> 3) << 2) + (tb & 3);
                        }
                        dst[(((size_t)(b * N_HEADS + h)) * SEQ_T + tt) * HEAD_DIM + dh] = f2bf(v);
                    } else {
                        ((unsigned short*)o2)[((size_t)(b * N_HEADS + h) * HEAD_DIM + dh) * SEQ_T + t] = f2bf(v);
                    }
                }
            }
        }
    }
}

// ---------------- flash attention v11: flash8 body, one job/block, 1024 blocks -------
// Lesson from v9/v10: waves/CU is the lever — per-tile work is ~12 us of issue across
// the chip but serializes at <2 waves/SIMD. v11 = v8's verified 4-wave 64-query body
// with the ti-loop removed: 32 qt x 32 bh = 1024 blocks x 4 waves = 16 waves/CU all
// co-resident (LDS 4x32KB=128KB, VGPR ~104).
// Balance: band j (=blockIdx>>5, dispatched first = heaviest) maps to qt quadruples
// {31-x, 16+x, 15-x, x} (x=j&7) — every 4-round CU slot sums to 66 tiles under
// round-robin; heavy-first hedges any assignment skew.
// L2: within a band, blocks with the same (i&7) share an XCD slot and get bh from
// {4c..4c+3} -> ~2MB K/V per XCD L2.
// K/V staged via global_load_lds (16B, XOR chunk swizzle), double-buffered, one
// barrier per tile. Softmax: absolute exp2 (folded scale), diag-tile-only mask,
// v_cvt_pk_bf16_f32 packing, setprio around MFMA clusters.
// Q: [BH,T,Dh] ; Kp: [BH,Tperm,Dh] (32-key permuted) ; Vt: [BH,Dh,T] ; Y: [B*T,D_MODEL]
__global__ __launch_bounds__(256) void flash11(
    const unsigned short* __restrict__ Q,
    const unsigned short* __restrict__ Kp,
    const unsigned short* __restrict__ Vt,
    unsigned short* __restrict__ Y)
{
    __shared__ unsigned short Ks[2][64 * 64];
    __shared__ unsigned short Vs[2][64 * 64];

    const int tid = threadIdx.x;
    const int w = tid >> 6, lane = tid & 63;
    const int col = lane & 15, quad = lane >> 4;

    const int j = blockIdx.x >> 5;               // band 0..31 (heavy first)
    const int x = j & 7, rnd = j >> 3;
    const int qt = (rnd == 0) ? (31 - x) : (rnd == 1) ? (16 + x)
                 : (rnd == 2) ? (15 - x) : x;    // quadruple sums uniform (66 tiles/CU)
    const int g = blockIdx.x & 31;
    const int bh = (g & 7) * 4 + (g >> 3);       // XCD slot c -> heads {4c..4c+3}
    const int b = bh >> 4, h = bh & 15;

    const unsigned short* qbase = Q + (size_t)bh * SEQ_T * HEAD_DIM;
    const unsigned short* kbase = Kp + (size_t)bh * SEQ_T * HEAD_DIM;
    const unsigned short* vbase = Vt + (size_t)bh * HEAD_DIM * SEQ_T;

    const int srow = lane >> 3;                  // 0..7 within the wave's 8 rows
    const int schunk = (lane & 7) ^ srow;        // XOR-swizzled source chunk
    const int cswz = col & 7;                    // reader swizzle key (row&7 == col&7)

    const float SC2 = 0.18033688011f;            // 0.125 * log2(e): exp(s/8)=exp2(s*SC2)
    const f32x4 zero = {0.f, 0.f, 0.f, 0.f};

    const int qrow = qt * 64 + w * 16;           // this wave's strip
    const short8 qf0 = *(const short8*)&qbase[(size_t)(qrow + col) * HEAD_DIM + quad * 8];
    const short8 qf1 = *(const short8*)&qbase[(size_t)(qrow + col) * HEAD_DIM + quad * 8 + 32];

    f32x4 acc[4];
#pragma unroll
    for (int nt = 0; nt < 4; nt++) acc[nt] = zero;
    float l = 0.f;

    const int nk = qt + 1;

    // prefetch kt=0 into buffer 0
#pragma unroll
    for (int rq = 0; rq < 2; rq++) {
        const int rr = rq * 32 + 8 * w;          // wave-uniform row base
        glds16(&kbase[(size_t)(rr + srow) * HEAD_DIM + schunk * 8], &Ks[0][rr * 64]);
        glds16(&vbase[(size_t)(rr + srow) * SEQ_T + schunk * 8], &Vs[0][rr * 64]);
    }

    int cur = 0;
    for (int kt = 0; kt < nk; kt++) {
        const int kb = kt * 64;
        __syncthreads();   // vmcnt(0) drain: buf[cur] ready; buf[cur^1] readers done

        if (kt + 1 < nk) {
            const int kb2 = kb + 64;
#pragma unroll
            for (int rq = 0; rq < 2; rq++) {
                const int rr = rq * 32 + 8 * w;
                glds16(&kbase[(size_t)(kb2 + rr + srow) * HEAD_DIM + schunk * 8], &Ks[cur ^ 1][rr * 64]);
                glds16(&vbase[(size_t)(rr + srow) * SEQ_T + kb2 + schunk * 8], &Vs[cur ^ 1][rr * 64]);
            }
        }

        const unsigned short* ks = Ks[cur];
        const unsigned short* vs = Vs[cur];

        // V B-frags from LDS (swizzled chunks)
        short8 vB[2][4];
#pragma unroll
        for (int gg = 0; gg < 2; gg++)
#pragma unroll
            for (int nt = 0; nt < 4; nt++)
                vB[gg][nt] = *(const short8*)&vs[(nt * 16 + col) * 64 + (((gg * 4 + quad) ^ cswz) * 8)];

        // St = K*Q^T over 4 16-key tiles (permuted storage rows)
        f32x4 St[4];
        __builtin_amdgcn_s_setprio(1);
#pragma unroll
        for (int kc = 0; kc < 4; kc++) {
            const short8 kf0 = *(const short8*)&ks[(kc * 16 + col) * 64 + ((quad ^ cswz) * 8)];
            const short8 kf1 = *(const short8*)&ks[(kc * 16 + col) * 64 + (((quad + 4) ^ cswz) * 8)];
            f32x4 z = zero;
            z = __builtin_amdgcn_mfma_f32_16x16x32_bf16(kf0, qf0, z, 0, 0, 0);
            z = __builtin_amdgcn_mfma_f32_16x16x32_bf16(kf1, qf1, z, 0, 0, 0);
            St[kc] = z;
        }
        __builtin_amdgcn_s_setprio(0);

        // p = exp2(s*SC2); causal mask only on the diagonal tile (uniform branch);
        // pack pairs via v_cvt_pk_bf16_f32; per-lane sum l.
        // actual key of St[kc][r] = kb + (kc>>1)*32 + quad*8 + (kc&1)*4 + r
        short8 pA[2];
        if (kt == nk - 1) {
#pragma unroll
            for (int gg = 0; gg < 2; gg++) {
                union { short8 s; __hip_bfloat162 h[4]; } pu;
#pragma unroll
                for (int t16 = 0; t16 < 2; t16++) {
                    const int kc = 2 * gg + t16;
                    const int kbase_c = kb + (kc >> 1) * 32 + quad * 8 + (kc & 1) * 4;
                    float p[4];
#pragma unroll
                    for (int r = 0; r < 4; r++) {
                        p[r] = __builtin_amdgcn_exp2f(St[kc][r] * SC2);
                        if (kbase_c + r > qrow + col) p[r] = 0.f;
                        l += p[r];
                    }
                    pu.h[t16 * 2]     = __float22bfloat162_rn(make_float2(p[0], p[1]));
                    pu.h[t16 * 2 + 1] = __float22bfloat162_rn(make_float2(p[2], p[3]));
                }
                pA[gg] = pu.s;
            }
        } else {
#pragma unroll
            for (int gg = 0; gg < 2; gg++) {
                union { short8 s; __hip_bfloat162 h[4]; } pu;
#pragma unroll
                for (int t16 = 0; t16 < 2; t16++) {
                    const int kc = 2 * gg + t16;
                    float p[4];
#pragma unroll
                    for (int r = 0; r < 4; r++) {
                        p[r] = __builtin_amdgcn_exp2f(St[kc][r] * SC2);
                        l += p[r];
                    }
                    pu.h[t16 * 2]     = __float22bfloat162_rn(make_float2(p[0], p[1]));
                    pu.h[t16 * 2 + 1] = __float22bfloat162_rn(make_float2(p[2], p[3]));
                }
                pA[gg] = pu.s;
            }
        }

        __builtin_amdgcn_s_setprio(1);
#pragma unroll
        for (int gg = 0; gg < 2; gg++)
#pragma unroll
            for (int nt = 0; nt < 4; nt++)
                acc[nt] = __builtin_amdgcn_mfma_f32_16x16x32_bf16(pA[gg], vB[gg][nt], acc[nt], 0, 0, 0);
        __builtin_amdgcn_s_setprio(0);

        cur ^= 1;
    }

    // one cross-lane reduction per strip
    l += __shfl_xor(l, 16);
    l += __shfl_xor(l, 32);
    const float linv = 1.0f / l;
    float lr[4];
#pragma unroll
    for (int r = 0; r < 4; r++) lr[r] = __shfl(linv, quad * 4 + r);
#pragma unroll
    for (int nt = 0; nt < 4; nt++)
#pragma unroll
        for (int r = 0; r < 4; r++) {
            const int qg = qrow + quad * 4 + r;
            Y[((size_t)(b * SEQ_T + qg)) * D_MODEL + h * HEAD_DIM + nt * 16 + col] = f2bf(acc[nt][r] * lr[r]);
        }
}

extern "C" void kernel_launch(void* const* d_in, const int* in_sizes, int n_in,
                              void* d_out, int out_size, void* d_ws, size_t ws_size,
                              hipStream_t stream) {
    const float* x  = (const float*)d_in[0];
    const float* Wq = (const float*)d_in[1];
    const float* bq = (const float*)d_in[2];
    const float* Wk = (const float*)d_in[3];
    const float* bk = (const float*)d_in[4];
    const float* Wv = (const float*)d_in[5];
    const float* bv = (const float*)d_in[6];
    const float* Wp = (const float*)d_in[7];
    const float* bp = (const float*)d_in[8];
    float* out = (float*)d_out;

    char* ws = (char*)d_ws;
    const size_t XSZ = (size_t)4096 * 1024 * 2;
    unsigned short* xb  = (unsigned short*)ws;  ws += XSZ;
    unsigned short* wb  = (unsigned short*)ws;  ws += (size_t)3072 * 1024 * 2;
    unsigned short* wpb = (unsigned short*)ws;  ws += (size_t)1024 * 1024 * 2;
    unsigned short* qb  = (unsigned short*)ws;  ws += XSZ;
    unsigned short* kb  = (unsigned short*)ws;  ws += XSZ;  // permuted keys
    unsigned short* vtb = (unsigned short*)ws;  ws += XSZ;
    unsigned short* yb  = (unsigned short*)ws;  ws += XSZ;

    cvt_all<<<8192, 256, 0, stream>>>((const float4*)x, (const float4*)Wq, (const float4*)Wk,
                                      (const float4*)Wv, (const float4*)Wp,
                                      (ushort4*)xb, (ushort4*)wb, (ushort4*)wpb);

    gemm2<3, 128><<<dim3(24, 32), 256, 0, stream>>>(xb, wb, bq, bk, bv, qb, kb, vtb);

    flash11<<<1024, 256, 0, stream>>>(qb, kb, vtb, yb);

    gemm2<2, 64><<<dim3(8, 64), 256, 0, stream>>>(yb, wpb, bp, nullptr, nullptr, out, nullptr, nullptr);
}